// Round 2
// baseline (720.301 us; speedup 1.0000x reference)
//
#include <hip/hip_runtime.h>

#define M_OUT   125000
#define CIN     96
#define COUT    192
#define KOCT    8
#define MT      128      // rows per block: 4 row-groups x 32 rows
#define LDB     104      // padded bf16 stride for weights (96+8); 208 B rows
#define BN_EPS  1e-5f

// ws layout (floats at base):
//   [0,192) sums   [192,384) sumsq
// byte 4096: bf16 WT[k][n][c_pad104]  (8*192*104*2 = 319488 B)
#define WS_WT_BYTE   4096

typedef __attribute__((ext_vector_type(8))) short bf16x8;
typedef __attribute__((ext_vector_type(4))) float f32x4;

__device__ __forceinline__ unsigned short f2bf(float f) {
    unsigned int u = __float_as_uint(f);
    u += 0x7FFF + ((u >> 16) & 1);           // RNE
    return (unsigned short)(u >> 16);
}

__device__ __forceinline__ unsigned int pack2(float a, float b) {
    unsigned int ua = __float_as_uint(a);
    unsigned int ub = __float_as_uint(b);
    ua += 0x7FFF + ((ua >> 16) & 1);
    ub += 0x7FFF + ((ub >> 16) & 1);
    return (ua >> 16) | (ub & 0xFFFF0000u);
}

__device__ __forceinline__ bf16x8 pack8(const float4 h0, const float4 h1) {
    union { unsigned int u[4]; bf16x8 v; } r;
    r.u[0] = pack2(h0.x, h0.y);
    r.u[1] = pack2(h0.z, h0.w);
    r.u[2] = pack2(h1.x, h1.y);
    r.u[3] = pack2(h1.z, h1.w);
    return r.v;
}

// select octant k's index out of two int4s (k constant after unroll -> folds)
__device__ __forceinline__ int sel8(const int4 a, const int4 b, int k) {
    switch (k & 7) {
        case 0: return a.x; case 1: return a.y; case 2: return a.z; case 3: return a.w;
        case 4: return b.x; case 5: return b.y; case 6: return b.z; default: return b.w;
    }
}

// ---------------- prep: zero stats + build bf16 transposed padded weights ----
__global__ void prep_kernel(const float* __restrict__ W, float* __restrict__ ws_f,
                            unsigned short* __restrict__ wt) {
    int gid = blockIdx.x * blockDim.x + threadIdx.x;
    if (gid < 384) ws_f[gid] = 0.0f;
    if (gid < KOCT * COUT * LDB) {
        int c = gid % LDB;
        int rest = gid / LDB;
        int n = rest % COUT;
        int k = rest / COUT;
        float v = (c < CIN) ? W[(k * CIN + c) * COUT + n] : 0.0f;
        wt[gid] = f2bf(v);
    }
}

// ---------------- conv: barrier-free per-wave register gather-GEMM ----------
// 512 threads = 8 waves = 4 row-groups x 2 col-halves.
// Wave owns 32 rows x 96 cols. A gathered straight to registers, 2 octants
// deep. B fragments read directly from global (L2-hot), 1 ks-group ahead.
// NO __syncthreads in the octant loop -> waves self-pipeline, no convoy.
__global__ __launch_bounds__(512, 2)
void conv_kernel(const float* __restrict__ data,
                 const int* __restrict__ neigh,
                 const float* __restrict__ bias,
                 const unsigned short* __restrict__ wt,
                 float* __restrict__ out,
                 float* __restrict__ gsum) {
    __shared__ float stats[2 * COUT];           // 1536 B (only LDS in kernel)

    const int t    = threadIdx.x;
    const int wave = t >> 6;
    const int lane = t & 63;
    const int quad = lane >> 4;
    const int l15  = lane & 15;
    const int rg   = wave >> 1;   // 0..3 row group (32 rows each)
    const int ch   = wave & 1;    // 0..1 col half (96 cols each)
    const int m0   = blockIdx.x * MT;
    const int row0 = m0 + rg * 32;

    for (int i = t; i < 2 * COUT; i += 512) stats[i] = 0.0f;
    __syncthreads();              // publish zeroed stats before epilogue atomics

    // this lane's neighbor indices: 2 row-tiles x 8 octants
    int4 nid[2][2];
#pragma unroll
    for (int rt = 0; rt < 2; ++rt) {
        int gm = row0 + rt * 16 + l15;
        if (gm < M_OUT) {
            nid[rt][0] = *reinterpret_cast<const int4*>(neigh + (size_t)gm * 8);
            nid[rt][1] = *reinterpret_cast<const int4*>(neigh + (size_t)gm * 8 + 4);
        } else {
            nid[rt][0] = make_int4(-1, -1, -1, -1);
            nid[rt][1] = make_int4(-1, -1, -1, -1);
        }
    }

    f32x4 acc[2][6];
    const f32x4 vz = {0.f, 0.f, 0.f, 0.f};
#pragma unroll
    for (int i = 0; i < 2; ++i)
#pragma unroll
        for (int j = 0; j < 6; ++j) acc[i][j] = vz;

    float4 arA[12], arB[12];      // 2-deep gather pipeline (fp32, in flight)
    bf16x8 af[2][3];              // current octant's packed A fragments

    // issue octant K's gathers into AR: 2 rows x 3 ks x 2 halves of float4
    auto gather = [&](float4 (&AR)[12], int K) {
#pragma unroll
        for (int rt = 0; rt < 2; ++rt) {
            int idx = sel8(nid[rt][0], nid[rt][1], K);
            const float* p = data + (size_t)idx * CIN + quad * 8;
#pragma unroll
            for (int ks = 0; ks < 3; ++ks)
#pragma unroll
                for (int h = 0; h < 2; ++h) {
                    float4 v = {0.f, 0.f, 0.f, 0.f};
                    if (idx >= 0) v = *reinterpret_cast<const float4*>(p + ks * 32 + h * 4);
                    AR[(rt * 3 + ks) * 2 + h] = v;
                }
        }
    };
    auto packA = [&](float4 (&AR)[12]) {
#pragma unroll
        for (int rt = 0; rt < 2; ++rt)
#pragma unroll
            for (int ks = 0; ks < 3; ++ks)
                af[rt][ks] = pack8(AR[(rt * 3 + ks) * 2], AR[(rt * 3 + ks) * 2 + 1]);
    };
    // load one ks-group of B fragments straight from global (L2-hot)
    auto loadB = [&](bf16x8 (&BF)[6], int K, int KS) {
#pragma unroll
        for (int c = 0; c < 6; ++c) {
            int n = ch * 96 + c * 16 + l15;
            BF[c] = *reinterpret_cast<const bf16x8*>(
                wt + ((size_t)K * COUT + n) * LDB + KS * 32 + quad * 8);
        }
    };
    auto mfmaG = [&](bf16x8 (&BF)[6], int KS) {
#pragma unroll
        for (int rt = 0; rt < 2; ++rt)
#pragma unroll
            for (int c = 0; c < 6; ++c)
                acc[rt][c] = __builtin_amdgcn_mfma_f32_16x16x32_bf16(
                    af[rt][KS], BF[c], acc[rt][c], 0, 0, 0);
    };

    // prologue: octants 0 and 1 in flight
    gather(arA, 0);
    gather(arB, 1);

    bf16x8 b0[6], b1[6];
#pragma unroll
    for (int k = 0; k < KOCT; ++k) {
        loadB(b0, k, 0);                    // first B group in flight
        if (k & 1) packA(arB); else packA(arA);   // waits octant k's gathers
        if (k < KOCT - 2) {                 // reuse freed regs: gather k+2
            if (k & 1) gather(arB, k + 2); else gather(arA, k + 2);
        }
        loadB(b1, k, 1);                    // second B group in flight
        __builtin_amdgcn_sched_barrier(0);  // keep all issues above the MFMAs
        mfmaG(b0, 0);
        loadB(b0, k, 2);                    // third B group (reuses b0)
        mfmaG(b1, 1);
        mfmaG(b0, 2);
    }

    // ---- epilogue: + bias, store conv-out fp32, per-channel sum/sumsq
#pragma unroll
    for (int ct = 0; ct < 6; ++ct) {
        int col = ch * 96 + ct * 16 + l15;
        float b = bias[col];
        float s1 = 0.f, s2 = 0.f;
#pragma unroll
        for (int rt = 0; rt < 2; ++rt) {
#pragma unroll
            for (int r = 0; r < 4; ++r) {
                int gm = row0 + rt * 16 + quad * 4 + r;
                if (gm < M_OUT) {
                    float v = acc[rt][ct][r] + b;
                    out[(size_t)gm * COUT + col] = v;
                    s1 += v;
                    s2 += v * v;
                }
            }
        }
        // reduce across the 4 quads (same col) before touching LDS
        s1 += __shfl_xor(s1, 16); s2 += __shfl_xor(s2, 16);
        s1 += __shfl_xor(s1, 32); s2 += __shfl_xor(s2, 32);
        if (quad == 0) {
            atomicAdd(&stats[col], s1);
            atomicAdd(&stats[COUT + col], s2);
        }
    }
    __syncthreads();
    for (int i = t; i < COUT; i += 512) {
        atomicAdd(&gsum[i], stats[i]);
        atomicAdd(&gsum[COUT + i], stats[COUT + i]);
    }
}

// ---------------- normalize (finalize folded in): y = x*scale[c] + shift[c] -
__global__ void norm_kernel(float* __restrict__ out,
                            const float* __restrict__ gsum,
                            const float* __restrict__ gamma,
                            const float* __restrict__ beta) {
    __shared__ float s_scale[COUT], s_shift[COUT];
    for (int i = threadIdx.x; i < COUT; i += blockDim.x) {
        const float inv_m = 1.0f / (float)M_OUT;
        float mean = gsum[i] * inv_m;
        float var  = gsum[COUT + i] * inv_m - mean * mean;
        float sc   = gamma[i] * rsqrtf(var + BN_EPS);
        s_scale[i] = sc;
        s_shift[i] = beta[i] - mean * sc;
    }
    __syncthreads();
    const int total4 = M_OUT * COUT / 4;   // 6,000,000
    int stride = gridDim.x * blockDim.x;
    for (int i = blockIdx.x * blockDim.x + threadIdx.x; i < total4; i += stride) {
        float4 v = reinterpret_cast<float4*>(out)[i];
        int c4 = (i % (COUT / 4)) * 4;
        v.x = v.x * s_scale[c4 + 0] + s_shift[c4 + 0];
        v.y = v.y * s_scale[c4 + 1] + s_shift[c4 + 1];
        v.z = v.z * s_scale[c4 + 2] + s_shift[c4 + 2];
        v.w = v.w * s_scale[c4 + 3] + s_shift[c4 + 3];
        reinterpret_cast<float4*>(out)[i] = v;
    }
}

extern "C" void kernel_launch(void* const* d_in, const int* in_sizes, int n_in,
                              void* d_out, int out_size, void* d_ws, size_t ws_size,
                              hipStream_t stream) {
    const float* data  = (const float*)d_in[0];
    const float* W     = (const float*)d_in[1];
    const float* bias  = (const float*)d_in[2];
    const float* gamma = (const float*)d_in[3];
    const float* beta  = (const float*)d_in[4];
    const int*   neigh = (const int*)d_in[5];
    float* out  = (float*)d_out;
    float* ws_f = (float*)d_ws;
    unsigned short* wt = (unsigned short*)((char*)d_ws + WS_WT_BYTE);

    // 1. prep: zero stats, build bf16 weights (8*192*104 = 159744 elems)
    prep_kernel<<<(KOCT * COUT * LDB + 255) / 256, 256, 0, stream>>>(W, ws_f, wt);

    // 2. barrier-free gather-GEMM conv + stat accumulation
    int grid1 = (M_OUT + MT - 1) / MT;   // 977
    conv_kernel<<<grid1, 512, 0, stream>>>(data, neigh, bias, wt, out, ws_f);

    // 3. in-place normalize (computes scale/shift from gsum per block)
    norm_kernel<<<4096, 256, 0, stream>>>(out, ws_f, gamma, beta);
}

// Round 4
// 644.225 us; speedup vs baseline: 1.1181x; 1.1181x over previous
//
#include <hip/hip_runtime.h>

#define M_OUT   125000
#define CIN     96
#define COUT    192
#define KOCT    8
#define MT      128      // rows per block
#define LDB     104      // padded bf16 stride for weights (96+8); 208 B rows
#define BN_EPS  1e-5f

// ws layout (floats at base): [0,192) sums   [192,384) sumsq
// byte 4096: bf16 WT[k][n][c_pad104]  (8*192*104*2 = 319488 B)
#define WS_WT_BYTE   4096

typedef __attribute__((ext_vector_type(8))) short bf16x8;
typedef __attribute__((ext_vector_type(4))) float f32x4;

__device__ __forceinline__ unsigned short f2bf(float f) {
    unsigned int u = __float_as_uint(f);
    u += 0x7FFF + ((u >> 16) & 1);           // RNE
    return (unsigned short)(u >> 16);
}

__device__ __forceinline__ unsigned int pack2(float a, float b) {
    unsigned int ua = __float_as_uint(a);
    unsigned int ub = __float_as_uint(b);
    ua += 0x7FFF + ((ua >> 16) & 1);
    ub += 0x7FFF + ((ub >> 16) & 1);
    return (ua >> 16) | (ub & 0xFFFF0000u);
}

__device__ __forceinline__ bf16x8 pack8(const float4 h0, const float4 h1) {
    union { unsigned int u[4]; bf16x8 v; } r;
    r.u[0] = pack2(h0.x, h0.y);
    r.u[1] = pack2(h0.z, h0.w);
    r.u[2] = pack2(h1.x, h1.y);
    r.u[3] = pack2(h1.z, h1.w);
    return r.v;
}

// select octant k's index out of two int4s (runtime k -> cndmask tree)
__device__ __forceinline__ int sel8(const int4 a, const int4 b, int k) {
    switch (k & 7) {
        case 0: return a.x; case 1: return a.y; case 2: return a.z; case 3: return a.w;
        case 4: return b.x; case 5: return b.y; case 6: return b.z; default: return b.w;
    }
}

// ---------------- prep: zero stats + build bf16 transposed padded weights ----
__global__ void prep_kernel(const float* __restrict__ W, float* __restrict__ ws_f,
                            unsigned short* __restrict__ wt) {
    int gid = blockIdx.x * blockDim.x + threadIdx.x;
    if (gid < 384) ws_f[gid] = 0.0f;
    if (gid < KOCT * COUT * LDB) {
        int c = gid % LDB;
        int rest = gid / LDB;
        int n = rest % COUT;
        int k = rest / COUT;
        float v = (c < CIN) ? W[(k * CIN + c) * COUT + n] : 0.0f;
        wt[gid] = f2bf(v);
    }
}

// ---------------- conv: LDS-pipelined gather-GEMM ---------------------------
// A-tile (128 rows x 96 ch fp32, 48KB) staged via global_load_lds with
// PER-LANE gather source addresses, triple-buffered -> async engine holds the
// in-flight depth (no VGPR cost). B read direct from global (L2-hot), issued
// BEFORE each stage so the compiler's counted B-waits drain stage(k+1) (needed
// next iter anyway) and never the just-issued stage(k+2). Raw s_barrier at the
// publish points (no vmcnt(0) drain). XOR-16B LDS swizzle via pre-swizzled
// global source + swizzled read (both-sides rule).
__global__ __launch_bounds__(512, 2)
void conv_kernel(const float* __restrict__ data,
                 const int* __restrict__ neigh,
                 const float* __restrict__ bias,
                 const unsigned short* __restrict__ wt,
                 float* __restrict__ out,
                 float* __restrict__ gsum) {
    __shared__ __align__(16) float Abuf[3][MT * CIN];   // 3 x 49152 B
    __shared__ int   idxs[MT * KOCT];                   // 4096 B (clamped)
    __shared__ float stats[2 * COUT];                   // 1536 B

    const int t    = threadIdx.x;
    const int wave = t >> 6;
    const int lane = t & 63;
    const int quad = lane >> 4;
    const int l15  = lane & 15;
    const int rg   = wave >> 1;   // 0..3 row group (32 rows)
    const int ch   = wave & 1;    // 0..1 col half (96 cols)
    const int m0   = blockIdx.x * MT;
    const int row0 = m0 + rg * 32;

    // stage clamped neighbor indices for all 128 rows x 8 octants
    if (t < 256) {
        int row = t >> 1, half = t & 1;
        int gm = m0 + row;
        int4 v = make_int4(0, 0, 0, 0);
        if (gm < M_OUT) v = *reinterpret_cast<const int4*>(neigh + (size_t)gm * 8 + half * 4);
        v.x = max(v.x, 0); v.y = max(v.y, 0); v.z = max(v.z, 0); v.w = max(v.w, 0);
        *reinterpret_cast<int4*>(idxs + row * 8 + half * 4) = v;
    }
    for (int i = t; i < 2 * COUT; i += 512) stats[i] = 0.0f;

    // raw indices for validity masking (this lane's 2 row-tiles)
    int4 nid[2][2];
#pragma unroll
    for (int rt = 0; rt < 2; ++rt) {
        int gm = row0 + rt * 16 + l15;
        if (gm < M_OUT) {
            nid[rt][0] = *reinterpret_cast<const int4*>(neigh + (size_t)gm * 8);
            nid[rt][1] = *reinterpret_cast<const int4*>(neigh + (size_t)gm * 8 + 4);
        } else {
            nid[rt][0] = make_int4(-1, -1, -1, -1);
            nid[rt][1] = make_int4(-1, -1, -1, -1);
        }
    }

    __syncthreads();   // idxs + stats published (full sync OK: no pipeline yet)

    // per-thread stage geometry (k-independent): 6 chunks of 16B
    int srow[6], scol[6];
#pragma unroll
    for (int i = 0; i < 6; ++i) {
        int off  = i * 8192 + t * 16;          // linear LDS byte offset
        int row  = off / 384;                  // 384 B = 96 fp32 per row
        int colb = off - row * 384;
        srow[i] = row;
        scol[i] = colb ^ ((row & 7) << 4);     // pre-swizzled SOURCE col
    }

    // issue octant k2's A-stage into buffer buf (6 global_load_lds / thread)
    auto stage = [&](int k2, int buf) {
        char* dst = (char*)&Abuf[buf][0];
#pragma unroll
        for (int i = 0; i < 6; ++i) {
            int idx = idxs[srow[i] * 8 + k2];                    // LDS (lgkm)
            const char* src = (const char*)data + (size_t)idx * 384 + scol[i];
            __builtin_amdgcn_global_load_lds(
                (const __attribute__((address_space(1))) unsigned int*)src,
                (__attribute__((address_space(3))) unsigned int*)(dst + i * 8192 + t * 16),
                16, 0, 0);
        }
    };

    f32x4 acc[2][6];
    const f32x4 vz = {0.f, 0.f, 0.f, 0.f};
#pragma unroll
    for (int i = 0; i < 2; ++i)
#pragma unroll
        for (int j = 0; j < 6; ++j) acc[i][j] = vz;

    const bf16x8 zfrag = {0, 0, 0, 0, 0, 0, 0, 0};

    // prologue: fill buffers 0,1
    stage(0, 0);
    asm volatile("s_waitcnt vmcnt(0)" ::: "memory");   // prologue-only drain
    stage(1, 1);

#pragma unroll 1
    for (int k = 0; k < KOCT; ++k) {
        bf16x8 bq[3][6];
        bf16x8 af[2][3];
        // ---- B loads FIRST (counted waits then drain stage(k+1), never k+2)
#pragma unroll
        for (int ks = 0; ks < 3; ++ks)
#pragma unroll
            for (int c = 0; c < 6; ++c) {
                int n = ch * 96 + c * 16 + l15;
                bq[ks][c] = *reinterpret_cast<const bf16x8*>(
                    wt + ((size_t)k * COUT + n) * LDB + ks * 32 + quad * 8);
            }
        __builtin_amdgcn_sched_barrier(0);
        if (k < KOCT - 2) stage(k + 2, (k + 2) % 3);
        __builtin_amdgcn_sched_barrier(0);
        __builtin_amdgcn_s_barrier();          // buf[k%3] published (raw: no drain)
        __builtin_amdgcn_sched_barrier(0);

        // ---- read A fp32 from LDS (swizzled), pack to bf16 fragments
        const char* abase = (const char*)&Abuf[k % 3][0];
#pragma unroll
        for (int rt = 0; rt < 2; ++rt) {
            int row   = rg * 32 + rt * 16 + l15;
            int rbase = row * 384;
            int sw    = (row & 7) << 4;
#pragma unroll
            for (int ks = 0; ks < 3; ++ks) {
                int c0 = ks * 128 + quad * 32;
                float4 v0 = *reinterpret_cast<const float4*>(abase + rbase + (c0 ^ sw));
                float4 v1 = *reinterpret_cast<const float4*>(abase + rbase + ((c0 + 16) ^ sw));
                af[rt][ks] = pack8(v0, v1);
            }
            int idxr = sel8(nid[rt][0], nid[rt][1], k);
            if (idxr < 0) { af[rt][0] = zfrag; af[rt][1] = zfrag; af[rt][2] = zfrag; }
        }
        // ---- 36 MFMA (bq consumed in issue order: counted vmcnt)
#pragma unroll
        for (int ks = 0; ks < 3; ++ks)
#pragma unroll
            for (int rt = 0; rt < 2; ++rt)
#pragma unroll
                for (int c = 0; c < 6; ++c)
                    acc[rt][c] = __builtin_amdgcn_mfma_f32_16x16x32_bf16(
                        af[rt][ks], bq[ks][c], acc[rt][c], 0, 0, 0);

        asm volatile("s_waitcnt lgkmcnt(0)" ::: "memory");  // ds_reads landed
        __builtin_amdgcn_sched_barrier(0);
        __builtin_amdgcn_s_barrier();          // all waves done reading buf[k%3]
        __builtin_amdgcn_sched_barrier(0);
    }

    // ---- epilogue: + bias, store conv-out fp32, per-channel sum/sumsq
#pragma unroll
    for (int ct = 0; ct < 6; ++ct) {
        int col = ch * 96 + ct * 16 + l15;
        float b = bias[col];
        float s1 = 0.f, s2 = 0.f;
#pragma unroll
        for (int rt = 0; rt < 2; ++rt) {
#pragma unroll
            for (int r = 0; r < 4; ++r) {
                int gm = row0 + rt * 16 + quad * 4 + r;
                if (gm < M_OUT) {
                    float v = acc[rt][ct][r] + b;
                    out[(size_t)gm * COUT + col] = v;
                    s1 += v;
                    s2 += v * v;
                }
            }
        }
        s1 += __shfl_xor(s1, 16); s2 += __shfl_xor(s2, 16);
        s1 += __shfl_xor(s1, 32); s2 += __shfl_xor(s2, 32);
        if (quad == 0) {
            atomicAdd(&stats[col], s1);
            atomicAdd(&stats[COUT + col], s2);
        }
    }
    __syncthreads();
    for (int i = t; i < COUT; i += 512) {
        atomicAdd(&gsum[i], stats[i]);
        atomicAdd(&gsum[COUT + i], stats[COUT + i]);
    }
}

// ---------------- normalize (finalize folded in): y = x*scale[c] + shift[c] -
__global__ void norm_kernel(float* __restrict__ out,
                            const float* __restrict__ gsum,
                            const float* __restrict__ gamma,
                            const float* __restrict__ beta) {
    __shared__ float s_scale[COUT], s_shift[COUT];
    for (int i = threadIdx.x; i < COUT; i += blockDim.x) {
        const float inv_m = 1.0f / (float)M_OUT;
        float mean = gsum[i] * inv_m;
        float var  = gsum[COUT + i] * inv_m - mean * mean;
        float sc   = gamma[i] * rsqrtf(var + BN_EPS);
        s_scale[i] = sc;
        s_shift[i] = beta[i] - mean * sc;
    }
    __syncthreads();
    const int total4 = M_OUT * COUT / 4;   // 6,000,000
    int stride = gridDim.x * blockDim.x;
    for (int i = blockIdx.x * blockDim.x + threadIdx.x; i < total4; i += stride) {
        float4 v = reinterpret_cast<float4*>(out)[i];
        int c4 = (i % (COUT / 4)) * 4;
        v.x = v.x * s_scale[c4 + 0] + s_shift[c4 + 0];
        v.y = v.y * s_scale[c4 + 1] + s_shift[c4 + 1];
        v.z = v.z * s_scale[c4 + 2] + s_shift[c4 + 2];
        v.w = v.w * s_scale[c4 + 3] + s_shift[c4 + 3];
        reinterpret_cast<float4*>(out)[i] = v;
    }
}

extern "C" void kernel_launch(void* const* d_in, const int* in_sizes, int n_in,
                              void* d_out, int out_size, void* d_ws, size_t ws_size,
                              hipStream_t stream) {
    const float* data  = (const float*)d_in[0];
    const float* W     = (const float*)d_in[1];
    const float* bias  = (const float*)d_in[2];
    const float* gamma = (const float*)d_in[3];
    const float* beta  = (const float*)d_in[4];
    const int*   neigh = (const int*)d_in[5];
    float* out  = (float*)d_out;
    float* ws_f = (float*)d_ws;
    unsigned short* wt = (unsigned short*)((char*)d_ws + WS_WT_BYTE);

    // 1. prep: zero stats, build bf16 weights
    prep_kernel<<<(KOCT * COUT * LDB + 255) / 256, 256, 0, stream>>>(W, ws_f, wt);

    // 2. LDS-pipelined gather-GEMM conv + stat accumulation
    int grid1 = (M_OUT + MT - 1) / MT;   // 977
    conv_kernel<<<grid1, 512, 0, stream>>>(data, neigh, bias, wt, out, ws_f);

    // 3. in-place normalize (computes scale/shift from gsum per block)
    norm_kernel<<<4096, 256, 0, stream>>>(out, ws_f, gamma, beta);
}